// Round 4
// baseline (180.412 us; speedup 1.0000x reference)
//
#include <hip/hip_runtime.h>

#define B_ 2048
#define K_ 32
#define D_ 256

typedef __attribute__((ext_vector_type(4))) float f32x4;

// Kernel 1: proj = node(2048x256) @ W(256x256), pure fp32.
// 512 blocks x 256 threads; block handles 4 rows; thread t owns column t.
__global__ __launch_bounds__(256) void proj_kernel(
    const float* __restrict__ node, const float* __restrict__ W,
    float* __restrict__ proj)
{
    __shared__ float nlds[4][D_];
    const int t = threadIdx.x;
    const int r0 = blockIdx.x * 4;
    for (int i = t; i < 4 * D_; i += 256)
        nlds[i >> 8][i & 255] = node[r0 * D_ + i];
    __syncthreads();
    float a0 = 0.f, a1 = 0.f, a2 = 0.f, a3 = 0.f;
    const float* Wc = W + t;
    #pragma unroll 8
    for (int d = 0; d < D_; ++d) {
        float w = Wc[d * D_];            // coalesced column read, L2-hot
        a0 += nlds[0][d] * w;
        a1 += nlds[1][d] * w;
        a2 += nlds[2][d] * w;
        a3 += nlds[3][d] * w;
    }
    proj[(r0 + 0) * D_ + t] = a0;
    proj[(r0 + 1) * D_ + t] = a1;
    proj[(r0 + 2) * D_ + t] = a2;
    proj[(r0 + 3) * D_ + t] = a3;
}

// Kernel 2: one block per b, 256 threads. Everything fp32, row-major LDS,
// no transposes, no MFMA.
//   S[k][n] = P[k] . N[n] + bias[n]   (P = proj rows 32*(b%64)..+32)
//   A = softmax_n(S);  out0 = A @ N;  out1 = A.
#define PSTR 260   // row stride in floats: 1040B, 16B-multiple

__global__ __launch_bounds__(256) void attn_kernel(
    const float* __restrict__ neigh,   // (B,K,D)
    const float* __restrict__ bias,    // (K,)
    const float* __restrict__ proj,    // (B,D)
    float* __restrict__ out0,          // (B,K,D)
    float* __restrict__ out1)          // (B,K,K)
{
    __shared__ __align__(16) float P[K_][PSTR];
    __shared__ __align__(16) float N[K_][PSTR];
    __shared__ float Sm[K_][K_ + 1];

    const int b = blockIdx.x;
    const int t = threadIdx.x;

    // ---- stage P and N (coalesced float4) ----
    const f32x4* psrc = (const f32x4*)(proj + (size_t)(32 * (b & 63)) * D_);
    const f32x4* nsrc = (const f32x4*)(neigh + (size_t)b * (K_ * D_));
    #pragma unroll
    for (int i = 0; i < 8; ++i) {
        int f = t + 256 * i;             // float4 index 0..2047
        int r = f >> 6, c4 = f & 63;     // row, float4-col
        *(f32x4*)(&P[r][c4 * 4]) = psrc[f];
        *(f32x4*)(&N[r][c4 * 4]) = nsrc[f];
    }
    __syncthreads();

    // ---- S phase: each thread computes a 2x2 block of S(32x32) ----
    {
        const int kp = t >> 4, np = t & 15;
        const int k0 = kp * 2, n0 = np * 2;
        float a00 = 0.f, a01 = 0.f, a10 = 0.f, a11 = 0.f;
        for (int dq = 0; dq < D_ / 4; ++dq) {
            f32x4 p0 = *(const f32x4*)(&P[k0][dq * 4]);
            f32x4 p1 = *(const f32x4*)(&P[k0 + 1][dq * 4]);
            f32x4 q0 = *(const f32x4*)(&N[n0][dq * 4]);
            f32x4 q1 = *(const f32x4*)(&N[n0 + 1][dq * 4]);
            #pragma unroll
            for (int j = 0; j < 4; ++j) {
                a00 += p0[j] * q0[j];
                a01 += p0[j] * q1[j];
                a10 += p1[j] * q0[j];
                a11 += p1[j] * q1[j];
            }
        }
        const float b0 = bias[n0], b1 = bias[n0 + 1];   // bias indexed by n (last axis)
        Sm[k0][n0]         = a00 + b0;
        Sm[k0][n0 + 1]     = a01 + b1;
        Sm[k0 + 1][n0]     = a10 + b0;
        Sm[k0 + 1][n0 + 1] = a11 + b1;
    }
    __syncthreads();

    // ---- softmax over n, one row per lane (t<32) ----
    if (t < K_) {
        float mx = -3.4e38f;
        for (int n = 0; n < K_; ++n) mx = fmaxf(mx, Sm[t][n]);
        float s = 0.f;
        for (int n = 0; n < K_; ++n) {
            float e = __expf(Sm[t][n] - mx);
            Sm[t][n] = e;
            s += e;
        }
        float inv = 1.f / s;
        for (int n = 0; n < K_; ++n) Sm[t][n] *= inv;
    }
    __syncthreads();

    // ---- A write-out (coalesced fp32) ----
    {
        float* oA = out1 + (size_t)b * (K_ * K_);
        #pragma unroll
        for (int i = 0; i < 4; ++i) {
            int idx = t + 256 * i;       // 0..1023
            oA[idx] = Sm[idx >> 5][idx & 31];
        }
    }

    // ---- PV phase: out0[k][d] = sum_n A[k][n] * N[n][d] ----
    {
        const int k = t >> 3, dq = t & 7;
        float* ob = out0 + (size_t)b * (K_ * D_) + k * D_;
        #pragma unroll
        for (int i = 0; i < 8; ++i) {
            const int c4 = 8 * i + dq;   // float4 column index 0..63
            f32x4 acc = {0.f, 0.f, 0.f, 0.f};
            for (int n = 0; n < K_; ++n) {
                const float a = Sm[k][n];          // broadcast within 8-lane group
                f32x4 q = *(const f32x4*)(&N[n][c4 * 4]);
                #pragma unroll
                for (int j = 0; j < 4; ++j) acc[j] += a * q[j];
            }
            *(f32x4*)(&ob[c4 * 4]) = acc;          // 16B-aligned global store
        }
    }
}

extern "C" void kernel_launch(void* const* d_in, const int* in_sizes, int n_in,
                              void* d_out, int out_size, void* d_ws, size_t ws_size,
                              hipStream_t stream)
{
    const float* node  = (const float*)d_in[0];   // (B,T,H) f32
    const float* neigh = (const float*)d_in[1];   // (B,K,T,H) f32
    const float* W     = (const float*)d_in[2];   // (D,D) f32
    const float* bias  = (const float*)d_in[3];   // (K,) f32

    float* proj = (float*)d_ws;                   // 2048*256 f32 = 2 MB scratch

    float* out0 = (float*)d_out;                  // (B,K,D) f32
    float* out1 = out0 + (size_t)B_ * K_ * D_;    // (B,K,K) f32

    proj_kernel<<<B_ / 4, 256, 0, stream>>>(node, W, proj);
    attn_kernel<<<B_, 256, 0, stream>>>(neigh, bias, proj, out0, out1);
}